// Round 10
// baseline (258.101 us; speedup 1.0000x reference)
//
#include <hip/hip_runtime.h>

using bf16x8   = __bf16 __attribute__((ext_vector_type(8)));
using floatx4  = float __attribute__((ext_vector_type(4)));
using floatx16 = float __attribute__((ext_vector_type(16)));

static __device__ __forceinline__ unsigned short f2b(float x) {
  unsigned u = __builtin_bit_cast(unsigned, x);
  u = (u + 0x7fffu + ((u >> 16) & 1u)) >> 16;  // RNE
  return (unsigned short)u;
}

// async global->LDS DMA, 16 B per lane. LDS dst = wave-uniform base + lane*16.
static __device__ __forceinline__ void gl_lds16(const unsigned short* g, unsigned short* l) {
  __builtin_amdgcn_global_load_lds((const __attribute__((address_space(1))) void*)g,
                                   (__attribute__((address_space(3))) void*)l, 16, 0, 0);
}

// ---- fused prep: x fp32->bf16 + 4 weight transposes (fp32 [R][C] -> bf16 [C][R])
__global__ __launch_bounds__(256) void prep_kernel(const float* __restrict__ x,
                                                   const float* __restrict__ Wq,
                                                   const float* __restrict__ Wk,
                                                   const float* __restrict__ Wv,
                                                   const float* __restrict__ Wu,
                                                   unsigned short* __restrict__ xb,
                                                   unsigned short* __restrict__ wqkt,
                                                   unsigned short* __restrict__ wvt,
                                                   unsigned short* __restrict__ wut) {
  int bx = blockIdx.x;
  if (bx < 1024) {  // x convert, 4 elems/thread
    int i = (bx * 256 + threadIdx.x) * 4;
    float4 v = *(const float4*)(x + i);
    unsigned long long p = (unsigned long long)f2b(v.x) |
                           ((unsigned long long)f2b(v.y) << 16) |
                           ((unsigned long long)f2b(v.z) << 32) |
                           ((unsigned long long)f2b(v.w) << 48);
    *(unsigned long long*)(xb + i) = p;
    return;
  }
  __shared__ unsigned short T[64][65];
  const float* src;
  unsigned short* dst;
  int R, C, tile;
  if (bx < 1152)      { src = Wq; dst = wqkt;          R = 256;  C = 2048; tile = bx - 1024; }
  else if (bx < 1280) { src = Wk; dst = wqkt + 524288; R = 256;  C = 2048; tile = bx - 1152; }
  else if (bx < 1408) { src = Wv; dst = wvt;           R = 256;  C = 2048; tile = bx - 1280; }
  else                { src = Wu; dst = wut;           R = 2048; C = 256;  tile = bx - 1408; }
  int ctiles = C >> 6;
  int cx = tile % ctiles, ry = tile / ctiles;
  int r0 = ry * 64, c0 = cx * 64;
  int t = threadIdx.x;
#pragma unroll
  for (int i = 0; i < 16; ++i) {
    int idx = i * 256 + t;
    int r = idx >> 6, c = idx & 63;
    T[r][c] = f2b(src[(size_t)(r0 + r) * C + c0 + c]);
  }
  __syncthreads();
#pragma unroll
  for (int i = 0; i < 16; ++i) {
    int idx = i * 256 + t;
    int c = idx >> 6, r = idx & 63;
    dst[(size_t)(c0 + c) * R + r0 + r] = T[r][c];
  }
}

// ---- fused QKV projection: 128x128 tiles, Kt=256; Q region pre-scaled 1/16
__global__ __launch_bounds__(256) void proj_kernel(const unsigned short* __restrict__ A,
                                                   const unsigned short* __restrict__ Bt,
                                                   unsigned short* __restrict__ qkb,
                                                   unsigned short* __restrict__ vtb) {
  __shared__ __align__(16) unsigned short SMEM[128 * 136];
  unsigned short* As = SMEM;
  unsigned short* Bs = SMEM + 4096;
  const int Kt = 256;
  int tid = threadIdx.x, lane = tid & 63, w = tid >> 6;
  int m16 = lane & 15, quad = lane >> 4;
  int wr = w & 1, wc = w >> 1;
  int m0 = blockIdx.y * 128, n0 = blockIdx.x * 128;
  int srow0 = w * 32 + (lane >> 2);
  int schunk = (lane & 3) ^ ((lane >> 2) & 3);
  floatx4 acc[4][4] = {};
  for (int k0 = 0; k0 < Kt; k0 += 32) {
    __syncthreads();
#pragma unroll
    for (int j = 0; j < 2; ++j) {
      int r = srow0 + j * 16;
      gl_lds16(A + (size_t)(m0 + r) * Kt + k0 + schunk * 8, &As[(w * 32 + j * 16) * 32]);
      gl_lds16(Bt + (size_t)(n0 + r) * Kt + k0 + schunk * 8, &Bs[(w * 32 + j * 16) * 32]);
    }
    __syncthreads();
    int sw = (quad ^ (m16 & 3)) * 8;
    bf16x8 af[4], bfr[4];
#pragma unroll
    for (int i = 0; i < 4; ++i) {
      af[i]  = *(const bf16x8*)(&As[(wr * 64 + i * 16 + m16) * 32 + sw]);
      bfr[i] = *(const bf16x8*)(&Bs[(wc * 64 + i * 16 + m16) * 32 + sw]);
    }
#pragma unroll
    for (int i = 0; i < 4; ++i)
#pragma unroll
      for (int jn = 0; jn < 4; ++jn)
        acc[i][jn] = __builtin_amdgcn_mfma_f32_16x16x32_bf16(af[i], bfr[jn], acc[i][jn], 0, 0, 0);
  }
  if (n0 < 4096) {
    float qscale = (n0 < 2048) ? 0.0625f : 1.0f;  // fold logit scale into Q (exact: 2^-4)
#pragma unroll
    for (int i = 0; i < 4; ++i)
#pragma unroll
      for (int jn = 0; jn < 4; ++jn)
#pragma unroll
        for (int r = 0; r < 4; ++r) {
          int m = m0 + wr * 64 + i * 16 + quad * 4 + r;
          int n = n0 + wc * 64 + jn * 16 + m16;
          qkb[(size_t)m * 4096 + n] = f2b(acc[i][jn][r] * qscale);
        }
  } else {
    __syncthreads();
    unsigned short* Vt = SMEM;  // [128 d][136]
#pragma unroll
    for (int i = 0; i < 4; ++i)
#pragma unroll
      for (int jn = 0; jn < 4; ++jn)
#pragma unroll
        for (int r = 0; r < 4; ++r) {
          int nn = wc * 64 + jn * 16 + m16;
          int mm = wr * 64 + i * 16 + quad * 4 + r;
          Vt[nn * 136 + mm] = f2b(acc[i][jn][r]);
        }
    __syncthreads();
    int bb = m0 >> 11, t0 = m0 & 2047;
#pragma unroll
    for (int i2 = 0; i2 < 8; ++i2) {
      int idx = i2 * 256 + tid;
      int nn = idx >> 4;
      int mc = (idx & 15) * 8;
      uint4 v = *(const uint4*)(&Vt[nn * 136 + mc]);
      *(uint4*)(&vtb[((size_t)(bb * 2048 + n0 - 4096 + nn)) * 2048 + t0 + mc]) = v;
    }
  }
}

// ---- out projection: 64x64 tiles, BK=128 ---------------------------------
__global__ __launch_bounds__(256) void out_kernel(const unsigned short* __restrict__ A,
                                                  const unsigned short* __restrict__ Bt,
                                                  float* __restrict__ Cout,
                                                  const float* __restrict__ bias) {
  __shared__ unsigned short As[64 * 128];
  __shared__ unsigned short Bs[64 * 128];
  const int Kt = 2048;
  int tid = threadIdx.x, lane = tid & 63, w = tid >> 6;
  int m16 = lane & 15, quad = lane >> 4;
  int m0 = blockIdx.y * 64, n0 = blockIdx.x * 64;
  int srow_i = lane >> 4;
  int spos = lane & 15;
  int rsw = m16 & 7;
  floatx4 acc[4] = {};
  for (int k0 = 0; k0 < Kt; k0 += 128) {
    __syncthreads();
#pragma unroll
    for (int j = 0; j < 4; ++j) {
      int r = w * 16 + j * 4 + srow_i;
      gl_lds16(A + (size_t)(m0 + r) * Kt + k0 + ((spos ^ (r & 7)) * 8), &As[(w * 16 + j * 4) * 128]);
      gl_lds16(Bt + (size_t)(n0 + r) * Kt + k0 + ((spos ^ (r & 7)) * 8), &Bs[(w * 16 + j * 4) * 128]);
    }
    __syncthreads();
    bf16x8 af[4];
#pragma unroll
    for (int kk = 0; kk < 4; ++kk)
      af[kk] = *(const bf16x8*)(&As[(w * 16 + m16) * 128 + (((kk * 4 + quad) ^ rsw) * 8)]);
#pragma unroll
    for (int nt = 0; nt < 4; ++nt)
#pragma unroll
      for (int kk = 0; kk < 4; ++kk) {
        bf16x8 bfv = *(const bf16x8*)(&Bs[(nt * 16 + m16) * 128 + (((kk * 4 + quad) ^ rsw) * 8)]);
        acc[nt] = __builtin_amdgcn_mfma_f32_16x16x32_bf16(af[kk], bfv, acc[nt], 0, 0, 0);
      }
  }
#pragma unroll
  for (int nt = 0; nt < 4; ++nt)
#pragma unroll
    for (int r = 0; r < 4; ++r) {
      int m = m0 + w * 16 + quad * 4 + r;
      int n = n0 + nt * 16 + m16;
      Cout[(size_t)m * 256 + n] = acc[nt][r] + bias[n];
    }
}

// ---- flash attention v4: fat waves (1 wave/SIMD, ~450 VGPR) --------------
// 4 waves = (u s-half, qsub). Wave: 64 q (2 qg) x s-half u x FULL d=256.
// kf reads reused across 2 qg (QK), vf reads reused across 2 qg (PV):
// 64 MFMA / 36 b128 reads per wave-iter (1.9x better than v3).
// K/V double-buffered DMA, 1 barrier/iter, wave-private P, cross-u epilogue.
__global__ __launch_bounds__(256, 1) void attn_kernel(const unsigned short* __restrict__ qk,
                                                      const unsigned short* __restrict__ vt,
                                                      unsigned short* __restrict__ ao) {
  __shared__ __align__(16) unsigned char SM[150528];
  unsigned short* KsBuf = (unsigned short*)SM;             // [2][64*256]  64 KB
  unsigned short* VsBuf = (unsigned short*)(SM + 65536);   // [2][256*64]  64 KB
  // P per wave: [2 qg][32 q][36 s] bf16 = 4608 B; 4 waves at SM+131072
  float* lsh = (float*)(SM + 149504);                      // [2 u][2 qsub][64 q] = 1 KB
  int tid = threadIdx.x, lane = tid & 63, w = tid >> 6;    // w 0..3
  int c32 = lane & 31, hi = lane >> 5;
  int qsub = w & 1, u = w >> 1;
  unsigned short* Pw = (unsigned short*)(SM + 131072) + w * 2304;
  int id = blockIdx.x;
  int xcd = id & 7, j = id >> 3;
  int bh = xcd + 8 * (j & 1);
  int q0 = (j >> 1) * 128;
  int b = bh >> 3, h = bh & 7;

  // Q B-frags (pre-scaled by 1/16 at proj): B[k=d][n=q], q = qsub*64+qg*32+c32
  bf16x8 qf[2][16];
#pragma unroll
  for (int qg = 0; qg < 2; ++qg) {
    const unsigned short* qrow =
        qk + (size_t)(b * 2048 + q0 + qsub * 64 + qg * 32 + c32) * 4096 + h * 256 + hi * 8;
#pragma unroll
    for (int kk = 0; kk < 16; ++kk) qf[qg][kk] = *(const bf16x8*)(qrow + kk * 16);
  }

  floatx16 O[2][8] = {};  // [qg][dt]: 64q x 256d partial over s-half u
  float lacc[2] = {0.f, 0.f};

  const unsigned short* kbase = qk + (size_t)b * 2048 * 4096 + 2048 + h * 256;
  const unsigned short* vbase = vt + (size_t)bh * 256 * 2048;

  int krow_i = lane >> 5, kpos = lane & 31;
  int vrow_i = lane >> 3, vpos = lane & 7;
  int ksw = c32 & 7;

  // prologue: stage tile 0 into buf 0 (wave w: K rows w*16.., V rows w*64..)
#pragma unroll
  for (int i = 0; i < 8; ++i) {
    int kr = i * 2 + krow_i;
    gl_lds16(kbase + (size_t)(w * 16 + kr) * 4096 + ((kpos ^ (kr & 7)) * 8),
             KsBuf + (w * 16 + i * 2) * 256);
    int vr = i * 8 + vrow_i;
    gl_lds16(vbase + (size_t)(w * 64 + vr) * 2048 + ((vpos ^ vrow_i) * 8),
             VsBuf + (w * 64 + i * 8) * 64);
  }

  for (int st = 0; st < 32; ++st) {
    int cur = st & 1;
    unsigned short* Kc = KsBuf + cur * 16384;
    unsigned short* Vc = VsBuf + cur * 16384;
    __syncthreads();  // drains DMA(cur); prior reads of (1-cur) done
    if (st < 31) {    // DMA st+1 into idle buffer (drains at next barrier)
      int s0 = (st + 1) * 64;
      unsigned short* kd = KsBuf + (1 - cur) * 16384;
      unsigned short* vd = VsBuf + (1 - cur) * 16384;
#pragma unroll
      for (int i = 0; i < 8; ++i) {
        int kr = i * 2 + krow_i;
        gl_lds16(kbase + (size_t)(s0 + w * 16 + kr) * 4096 + ((kpos ^ (kr & 7)) * 8),
                 kd + (w * 16 + i * 2) * 256);
        int vr = i * 8 + vrow_i;
        gl_lds16(vbase + (size_t)(w * 64 + vr) * 2048 + s0 + ((vpos ^ vrow_i) * 8),
                 vd + (w * 64 + i * 8) * 64);
      }
    }

    // S^T[u-half s][q] = K Q^T : one kf feeds BOTH qg chains
    floatx16 s0v = {}, s1v = {};
    const unsigned short* krl = Kc + (u * 32 + c32) * 256;
#pragma unroll
    for (int kk = 0; kk < 16; ++kk) {
      bf16x8 kf = *(const bf16x8*)(krl + (((kk * 2 + hi) ^ ksw) * 8));
      s0v = __builtin_amdgcn_mfma_f32_32x32x16_bf16(kf, qf[0][kk], s0v, 0, 0, 0);
      s1v = __builtin_amdgcn_mfma_f32_32x32x16_bf16(kf, qf[1][kk], s1v, 0, 0, 0);
    }
    // exp (scale already folded into Q) + rowsum + pack P (b64 = 4 consecutive s)
#pragma unroll
    for (int qg = 0; qg < 2; ++qg) {
      const floatx16& sv = qg ? s1v : s0v;
      unsigned short* Pq = Pw + qg * 1152;  // [32 q][36 s]
      float ls = 0.f;
#pragma unroll
      for (int g = 0; g < 4; ++g) {
        float p0 = __expf(sv[g * 4 + 0]);
        float p1 = __expf(sv[g * 4 + 1]);
        float p2 = __expf(sv[g * 4 + 2]);
        float p3 = __expf(sv[g * 4 + 3]);
        ls += p0 + p1 + p2 + p3;
        unsigned long long pk = (unsigned long long)f2b(p0) |
                                ((unsigned long long)f2b(p1) << 16) |
                                ((unsigned long long)f2b(p2) << 32) |
                                ((unsigned long long)f2b(p3) << 48);
        // s rows g*8 + hi*4 .. +3, col q=c32 -> P[q][s]
        *(unsigned long long*)(Pq + c32 * 36 + g * 8 + hi * 4) = pk;
      }
      lacc[qg] += ls;
    }
    // paf: A[m=q=c32][k=s=f*16+hi*8+j]  (wave-private, no barrier)
    bf16x8 paf[2][2];
#pragma unroll
    for (int qg = 0; qg < 2; ++qg)
#pragma unroll
      for (int f = 0; f < 2; ++f)
        paf[qg][f] = *(const bf16x8*)(Pw + qg * 1152 + c32 * 36 + f * 16 + hi * 8);
    // O += P V over full d=256: one vf feeds BOTH qg
#pragma unroll
    for (int dt = 0; dt < 8; ++dt) {
      const unsigned short* vrl = Vc + (dt * 32 + c32) * 64;
#pragma unroll
      for (int f = 0; f < 2; ++f) {
        bf16x8 vf = *(const bf16x8*)(vrl + (((u * 4 + f * 2 + hi) ^ ksw) * 8));
        O[0][dt] = __builtin_amdgcn_mfma_f32_32x32x16_bf16(paf[0][f], vf, O[0][dt], 0, 0, 0);
        O[1][dt] = __builtin_amdgcn_mfma_f32_32x32x16_bf16(paf[1][f], vf, O[1][dt], 0, 0, 0);
      }
    }
  }

  // epilogue: cross-u reduction of O and l, normalize, store
  float lw[2];
#pragma unroll
  for (int qg = 0; qg < 2; ++qg) lw[qg] = lacc[qg] + __shfl_xor(lacc[qg], 32);
  __syncthreads();  // all K/V/P reads done; SM reusable
  float* osh = (float*)SM;  // [2 qsub][64 q][256 d] fp32 = 128 KB
  if (u == 0) {
    float* od = osh + qsub * 16384;
#pragma unroll
    for (int qg = 0; qg < 2; ++qg)
#pragma unroll
      for (int dt = 0; dt < 8; ++dt)
#pragma unroll
        for (int i = 0; i < 16; ++i) {
          int ql = (i & 3) + 8 * (i >> 2) + 4 * hi;
          od[(qg * 32 + ql) * 256 + dt * 32 + c32] = O[qg][dt][i];
        }
  }
  if (hi == 0) {
#pragma unroll
    for (int qg = 0; qg < 2; ++qg)
      lsh[u * 128 + qsub * 64 + qg * 32 + c32] = lw[qg];
  }
  __syncthreads();
  if (u == 1) {
    float* od = osh + qsub * 16384;
    unsigned short* aor = ao + (size_t)(b * 2048 + q0 + qsub * 64) * 2048 + h * 256;
#pragma unroll
    for (int qg = 0; qg < 2; ++qg)
#pragma unroll
      for (int i = 0; i < 16; ++i) {
        int ql = (i & 3) + 8 * (i >> 2) + 4 * hi;
        int q = qg * 32 + ql;
        float lr = 1.0f / (lsh[qsub * 64 + q] + lsh[128 + qsub * 64 + q]);
#pragma unroll
        for (int dt = 0; dt < 8; ++dt) {
          float v = (O[qg][dt][i] + od[q * 256 + dt * 32 + c32]) * lr;
          aor[(size_t)q * 2048 + dt * 32 + c32] = f2b(v);
        }
      }
  }
}

extern "C" void kernel_launch(void* const* d_in, const int* in_sizes, int n_in,
                              void* d_out, int out_size, void* d_ws, size_t ws_size,
                              hipStream_t stream) {
  const float* x  = (const float*)d_in[0];
  const float* Wq = (const float*)d_in[1];
  const float* Wk = (const float*)d_in[2];
  const float* Wv = (const float*)d_in[3];
  const float* Wu = (const float*)d_in[4];
  const float* bu = (const float*)d_in[5];

  unsigned short* xb   = (unsigned short*)d_ws;      // [4096][256]
  unsigned short* wqkt = xb + 1048576;               // [4096][256]  Wq^T | Wk^T
  unsigned short* wvt  = wqkt + 1048576;             // [2048][256]  Wv^T (contiguous)
  unsigned short* wut  = wvt + 524288;               // [256][2048]  Wu^T
  unsigned short* qkb  = wut + 524288;               // [4096][4096] q | k
  unsigned short* vtb  = qkb + 16777216;             // [16][256][2048] V^T
  unsigned short* aob  = vtb + 8388608;              // [4096][2048] attn out

  prep_kernel<<<1536, 256, 0, stream>>>(x, Wq, Wk, Wv, Wu, xb, wqkt, wvt, wut);
  proj_kernel<<<dim3(48, 32), 256, 0, stream>>>(xb, wqkt, qkb, vtb);
  attn_kernel<<<256, 256, 0, stream>>>(qkb, vtb, aob);
  out_kernel<<<dim3(4, 64), 256, 0, stream>>>(aob, wut, (float*)d_out, bu);
}

// Round 11
// 193.736 us; speedup vs baseline: 1.3322x; 1.3322x over previous
//
#include <hip/hip_runtime.h>

using bf16x8   = __bf16 __attribute__((ext_vector_type(8)));
using floatx4  = float __attribute__((ext_vector_type(4)));
using floatx16 = float __attribute__((ext_vector_type(16)));

static __device__ __forceinline__ unsigned short f2b(float x) {
  unsigned u = __builtin_bit_cast(unsigned, x);
  u = (u + 0x7fffu + ((u >> 16) & 1u)) >> 16;  // RNE
  return (unsigned short)u;
}

// async global->LDS DMA, 16 B per lane. LDS dst = wave-uniform base + lane*16.
static __device__ __forceinline__ void gl_lds16(const unsigned short* g, unsigned short* l) {
  __builtin_amdgcn_global_load_lds((const __attribute__((address_space(1))) void*)g,
                                   (__attribute__((address_space(3))) void*)l, 16, 0, 0);
}

// ---- fused prep: x fp32->bf16 + 4 weight transposes (fp32 [R][C] -> bf16 [C][R])
__global__ __launch_bounds__(256) void prep_kernel(const float* __restrict__ x,
                                                   const float* __restrict__ Wq,
                                                   const float* __restrict__ Wk,
                                                   const float* __restrict__ Wv,
                                                   const float* __restrict__ Wu,
                                                   unsigned short* __restrict__ xb,
                                                   unsigned short* __restrict__ wqkt,
                                                   unsigned short* __restrict__ wvt,
                                                   unsigned short* __restrict__ wut) {
  int bx = blockIdx.x;
  if (bx < 1024) {  // x convert, 4 elems/thread
    int i = (bx * 256 + threadIdx.x) * 4;
    float4 v = *(const float4*)(x + i);
    unsigned long long p = (unsigned long long)f2b(v.x) |
                           ((unsigned long long)f2b(v.y) << 16) |
                           ((unsigned long long)f2b(v.z) << 32) |
                           ((unsigned long long)f2b(v.w) << 48);
    *(unsigned long long*)(xb + i) = p;
    return;
  }
  __shared__ unsigned short T[64][65];
  const float* src;
  unsigned short* dst;
  int R, C, tile;
  if (bx < 1152)      { src = Wq; dst = wqkt;          R = 256;  C = 2048; tile = bx - 1024; }
  else if (bx < 1280) { src = Wk; dst = wqkt + 524288; R = 256;  C = 2048; tile = bx - 1152; }
  else if (bx < 1408) { src = Wv; dst = wvt;           R = 256;  C = 2048; tile = bx - 1280; }
  else                { src = Wu; dst = wut;           R = 2048; C = 256;  tile = bx - 1408; }
  int ctiles = C >> 6;
  int cx = tile % ctiles, ry = tile / ctiles;
  int r0 = ry * 64, c0 = cx * 64;
  int t = threadIdx.x;
#pragma unroll
  for (int i = 0; i < 16; ++i) {
    int idx = i * 256 + t;
    int r = idx >> 6, c = idx & 63;
    T[r][c] = f2b(src[(size_t)(r0 + r) * C + c0 + c]);
  }
  __syncthreads();
#pragma unroll
  for (int i = 0; i < 16; ++i) {
    int idx = i * 256 + t;
    int c = idx >> 6, r = idx & 63;
    dst[(size_t)(c0 + c) * R + r0 + r] = T[r][c];
  }
}

// ---- fused QKV projection: 128x128 tiles, Kt=256; Q region pre-scaled 1/16
__global__ __launch_bounds__(256) void proj_kernel(const unsigned short* __restrict__ A,
                                                   const unsigned short* __restrict__ Bt,
                                                   unsigned short* __restrict__ qkb,
                                                   unsigned short* __restrict__ vtb) {
  __shared__ __align__(16) unsigned short SMEM[128 * 136];
  unsigned short* As = SMEM;
  unsigned short* Bs = SMEM + 4096;
  const int Kt = 256;
  int tid = threadIdx.x, lane = tid & 63, w = tid >> 6;
  int m16 = lane & 15, quad = lane >> 4;
  int wr = w & 1, wc = w >> 1;
  int m0 = blockIdx.y * 128, n0 = blockIdx.x * 128;
  int srow0 = w * 32 + (lane >> 2);
  int schunk = (lane & 3) ^ ((lane >> 2) & 3);
  floatx4 acc[4][4] = {};
  for (int k0 = 0; k0 < Kt; k0 += 32) {
    __syncthreads();
#pragma unroll
    for (int j = 0; j < 2; ++j) {
      int r = srow0 + j * 16;
      gl_lds16(A + (size_t)(m0 + r) * Kt + k0 + schunk * 8, &As[(w * 32 + j * 16) * 32]);
      gl_lds16(Bt + (size_t)(n0 + r) * Kt + k0 + schunk * 8, &Bs[(w * 32 + j * 16) * 32]);
    }
    __syncthreads();
    int sw = (quad ^ (m16 & 3)) * 8;
    bf16x8 af[4], bfr[4];
#pragma unroll
    for (int i = 0; i < 4; ++i) {
      af[i]  = *(const bf16x8*)(&As[(wr * 64 + i * 16 + m16) * 32 + sw]);
      bfr[i] = *(const bf16x8*)(&Bs[(wc * 64 + i * 16 + m16) * 32 + sw]);
    }
#pragma unroll
    for (int i = 0; i < 4; ++i)
#pragma unroll
      for (int jn = 0; jn < 4; ++jn)
        acc[i][jn] = __builtin_amdgcn_mfma_f32_16x16x32_bf16(af[i], bfr[jn], acc[i][jn], 0, 0, 0);
  }
  if (n0 < 4096) {
    float qscale = (n0 < 2048) ? 0.0625f : 1.0f;  // fold logit scale into Q (exact: 2^-4)
#pragma unroll
    for (int i = 0; i < 4; ++i)
#pragma unroll
      for (int jn = 0; jn < 4; ++jn)
#pragma unroll
        for (int r = 0; r < 4; ++r) {
          int m = m0 + wr * 64 + i * 16 + quad * 4 + r;
          int n = n0 + wc * 64 + jn * 16 + m16;
          qkb[(size_t)m * 4096 + n] = f2b(acc[i][jn][r] * qscale);
        }
  } else {
    __syncthreads();
    unsigned short* Vt = SMEM;  // [128 d][136]
#pragma unroll
    for (int i = 0; i < 4; ++i)
#pragma unroll
      for (int jn = 0; jn < 4; ++jn)
#pragma unroll
        for (int r = 0; r < 4; ++r) {
          int nn = wc * 64 + jn * 16 + m16;
          int mm = wr * 64 + i * 16 + quad * 4 + r;
          Vt[nn * 136 + mm] = f2b(acc[i][jn][r]);
        }
    __syncthreads();
    int bb = m0 >> 11, t0 = m0 & 2047;
#pragma unroll
    for (int i2 = 0; i2 < 8; ++i2) {
      int idx = i2 * 256 + tid;
      int nn = idx >> 4;
      int mc = (idx & 15) * 8;
      uint4 v = *(const uint4*)(&Vt[nn * 136 + mc]);
      *(uint4*)(&vtb[((size_t)(bb * 2048 + n0 - 4096 + nn)) * 2048 + t0 + mc]) = v;
    }
  }
}

// ---- out projection: 64x64 tiles, BK=128 ---------------------------------
__global__ __launch_bounds__(256) void out_kernel(const unsigned short* __restrict__ A,
                                                  const unsigned short* __restrict__ Bt,
                                                  float* __restrict__ Cout,
                                                  const float* __restrict__ bias) {
  __shared__ unsigned short As[64 * 128];
  __shared__ unsigned short Bs[64 * 128];
  const int Kt = 2048;
  int tid = threadIdx.x, lane = tid & 63, w = tid >> 6;
  int m16 = lane & 15, quad = lane >> 4;
  int m0 = blockIdx.y * 64, n0 = blockIdx.x * 64;
  int srow_i = lane >> 4;
  int spos = lane & 15;
  int rsw = m16 & 7;
  floatx4 acc[4] = {};
  for (int k0 = 0; k0 < Kt; k0 += 128) {
    __syncthreads();
#pragma unroll
    for (int j = 0; j < 4; ++j) {
      int r = w * 16 + j * 4 + srow_i;
      gl_lds16(A + (size_t)(m0 + r) * Kt + k0 + ((spos ^ (r & 7)) * 8), &As[(w * 16 + j * 4) * 128]);
      gl_lds16(Bt + (size_t)(n0 + r) * Kt + k0 + ((spos ^ (r & 7)) * 8), &Bs[(w * 16 + j * 4) * 128]);
    }
    __syncthreads();
    bf16x8 af[4];
#pragma unroll
    for (int kk = 0; kk < 4; ++kk)
      af[kk] = *(const bf16x8*)(&As[(w * 16 + m16) * 128 + (((kk * 4 + quad) ^ rsw) * 8)]);
#pragma unroll
    for (int nt = 0; nt < 4; ++nt)
#pragma unroll
      for (int kk = 0; kk < 4; ++kk) {
        bf16x8 bfv = *(const bf16x8*)(&Bs[(nt * 16 + m16) * 128 + (((kk * 4 + quad) ^ rsw) * 8)]);
        acc[nt] = __builtin_amdgcn_mfma_f32_16x16x32_bf16(af[kk], bfv, acc[nt], 0, 0, 0);
      }
  }
#pragma unroll
  for (int nt = 0; nt < 4; ++nt)
#pragma unroll
    for (int r = 0; r < 4; ++r) {
      int m = m0 + w * 16 + quad * 4 + r;
      int n = n0 + nt * 16 + m16;
      Cout[(size_t)m * 256 + n] = acc[nt][r] + bias[n];
    }
}

// ---- flash attention v2 (round-8 best, 97 us): BM=128, 512 threads -------
// 8 waves = 4 qg x 2 u. Double-buffered K/V DMA, 2 barriers/iter, shared P,
// ones-MFMA rowsum. Q pre-scaled 1/16 at proj -> no in-loop logit scale.
__global__ __launch_bounds__(512, 2) void attn_kernel(const unsigned short* __restrict__ qk,
                                                      const unsigned short* __restrict__ vt,
                                                      unsigned short* __restrict__ ao) {
  __shared__ __align__(16) unsigned short Ks[2][64 * 256];  // 64 KB
  __shared__ __align__(16) unsigned short Vs[2][256 * 64];  // 64 KB
  __shared__ __align__(16) unsigned short Pb[4][32 * 72];   // 18.4 KB
  int tid = threadIdx.x, lane = tid & 63, w = tid >> 6;  // w 0..7
  int c32 = lane & 31, hi = lane >> 5;
  int qg = w & 3, u = w >> 2;
  int id = blockIdx.x;
  int xcd = id & 7, j = id >> 3;
  int bh = xcd + 8 * (j & 1);
  int q0 = (j >> 1) * 128;
  int b = bh >> 3, h = bh & 7;

  // Q A-frags: rows q0+qg*32+c32, k = kk*16 + hi*8 + j  (pre-scaled by 1/16)
  bf16x8 qf[16];
  const unsigned short* qrow =
      qk + (size_t)(b * 2048 + q0 + qg * 32 + c32) * 4096 + h * 256 + hi * 8;
#pragma unroll
  for (int kk = 0; kk < 16; ++kk) qf[kk] = *(const bf16x8*)(qrow + kk * 16);

  bf16x8 onesf;
#pragma unroll
  for (int i = 0; i < 8; ++i) onesf[i] = (__bf16)1.0f;

  floatx16 O[4] = {};
  floatx16 l = {};

  const unsigned short* kbase = qk + (size_t)b * 2048 * 4096 + 2048 + h * 256;
  const unsigned short* vbase = vt + (size_t)bh * 256 * 2048;
  unsigned short* pq = &Pb[qg][0];

  int krow_i = lane >> 5, kpos = lane & 31;
  int vrow_i = lane >> 3, vpos = lane & 7;
  int ksw = c32 & 7;

  // prologue: stage tile 0 into buf 0 (4 K + 4 V DMA instr per wave)
#pragma unroll
  for (int i = 0; i < 4; ++i) {
    int kr = i * 2 + krow_i;
    gl_lds16(kbase + (size_t)(w * 8 + kr) * 4096 + ((kpos ^ (kr & 7)) * 8),
             &Ks[0][(w * 8 + i * 2) * 256]);
    int vr = i * 8 + vrow_i;
    gl_lds16(vbase + (size_t)(w * 32 + vr) * 2048 + ((vpos ^ vrow_i) * 8),
             &Vs[0][(w * 32 + i * 8) * 64]);
  }

  for (int st = 0; st < 32; ++st) {
    int cur = st & 1;
    __syncthreads();  // drains DMA(cur) (issued ~1 compute phase ago), publishes

    // S[32q][32s] = Q K^T over this wave's s-half u
    floatx16 s = {};
    const unsigned short* krl = &Ks[cur][(u * 32 + c32) * 256];
#pragma unroll
    for (int kk = 0; kk < 16; ++kk) {
      bf16x8 kf = *(const bf16x8*)(krl + (((kk * 2 + hi) ^ ksw) * 8));
      s = __builtin_amdgcn_mfma_f32_32x32x16_bf16(qf[kk], kf, s, 0, 0, 0);
    }
    // no-max softmax (scale folded into Q); P -> per-qg shared LDS
#pragma unroll
    for (int i = 0; i < 16; ++i) {
      float p = __expf(s[i]);
      int q = (i & 3) + 8 * (i >> 2) + 4 * hi;
      pq[q * 72 + u * 32 + c32] = f2b(p);
    }
    __syncthreads();  // P publish

    // issue DMA for st+1 into the idle buffer; drained at next top barrier
    if (st < 31) {
      int s0 = (st + 1) * 64;
      unsigned short* kdst = &Ks[1 - cur][0];
      unsigned short* vdst = &Vs[1 - cur][0];
#pragma unroll
      for (int i = 0; i < 4; ++i) {
        int kr = i * 2 + krow_i;
        gl_lds16(kbase + (size_t)(s0 + w * 8 + kr) * 4096 + ((kpos ^ (kr & 7)) * 8),
                 kdst + (w * 8 + i * 2) * 256);
        int vr = i * 8 + vrow_i;
        gl_lds16(vbase + (size_t)(w * 32 + vr) * 2048 + s0 + ((vpos ^ vrow_i) * 8),
                 vdst + (w * 32 + i * 8) * 64);
      }
    }

    // paf + rowsum + PV for this wave's d-half u
    bf16x8 paf[4];
#pragma unroll
    for (int f = 0; f < 4; ++f) paf[f] = *(const bf16x8*)(pq + c32 * 72 + f * 16 + hi * 8);
#pragma unroll
    for (int f = 0; f < 4; ++f)
      l = __builtin_amdgcn_mfma_f32_32x32x16_bf16(paf[f], onesf, l, 0, 0, 0);
#pragma unroll
    for (int dt = 0; dt < 4; ++dt) {
      const unsigned short* vrl = &Vs[cur][(u * 128 + dt * 32 + c32) * 64];
#pragma unroll
      for (int f = 0; f < 4; ++f) {
        bf16x8 vf = *(const bf16x8*)(vrl + (((f * 2 + hi) ^ ksw) * 8));
        O[dt] = __builtin_amdgcn_mfma_f32_32x32x16_bf16(paf[f], vf, O[dt], 0, 0, 0);
      }
    }
  }
  float inv[16];
#pragma unroll
  for (int i = 0; i < 16; ++i) inv[i] = 1.0f / l[i];
#pragma unroll
  for (int dt = 0; dt < 4; ++dt)
#pragma unroll
    for (int i = 0; i < 16; ++i) {
      int q = (i & 3) + 8 * (i >> 2) + 4 * hi;
      ao[(size_t)(b * 2048 + q0 + qg * 32 + q) * 2048 + h * 256 + u * 128 + dt * 32 + c32] =
          f2b(O[dt][i] * inv[i]);
    }
}

extern "C" void kernel_launch(void* const* d_in, const int* in_sizes, int n_in,
                              void* d_out, int out_size, void* d_ws, size_t ws_size,
                              hipStream_t stream) {
  const float* x  = (const float*)d_in[0];
  const float* Wq = (const float*)d_in[1];
  const float* Wk = (const float*)d_in[2];
  const float* Wv = (const float*)d_in[3];
  const float* Wu = (const float*)d_in[4];
  const float* bu = (const float*)d_in[5];

  unsigned short* xb   = (unsigned short*)d_ws;      // [4096][256]
  unsigned short* wqkt = xb + 1048576;               // [4096][256]  Wq^T | Wk^T
  unsigned short* wvt  = wqkt + 1048576;             // [2048][256]  Wv^T (contiguous)
  unsigned short* wut  = wvt + 524288;               // [256][2048]  Wu^T
  unsigned short* qkb  = wut + 524288;               // [4096][4096] q | k
  unsigned short* vtb  = qkb + 16777216;             // [16][256][2048] V^T
  unsigned short* aob  = vtb + 8388608;              // [4096][2048] attn out

  prep_kernel<<<1536, 256, 0, stream>>>(x, Wq, Wk, Wv, Wu, xb, wqkt, wvt, wut);
  proj_kernel<<<dim3(48, 32), 256, 0, stream>>>(xb, wqkt, qkb, vtb);
  attn_kernel<<<256, 512, 0, stream>>>(qkb, vtb, aob);
  out_kernel<<<dim3(4, 64), 256, 0, stream>>>(aob, wut, (float*)d_out, bu);
}

// Round 12
// 191.623 us; speedup vs baseline: 1.3469x; 1.0110x over previous
//
#include <hip/hip_runtime.h>

using bf16x8   = __bf16 __attribute__((ext_vector_type(8)));
using floatx4  = float __attribute__((ext_vector_type(4)));
using floatx16 = float __attribute__((ext_vector_type(16)));

static __device__ __forceinline__ unsigned short f2b(float x) {
  unsigned u = __builtin_bit_cast(unsigned, x);
  u = (u + 0x7fffu + ((u >> 16) & 1u)) >> 16;  // RNE
  return (unsigned short)u;
}

// async global->LDS DMA, 16 B per lane. LDS dst = wave-uniform base + lane*16.
static __device__ __forceinline__ void gl_lds16(const unsigned short* g, unsigned short* l) {
  __builtin_amdgcn_global_load_lds((const __attribute__((address_space(1))) void*)g,
                                   (__attribute__((address_space(3))) void*)l, 16, 0, 0);
}

// ---- fused prep: x fp32->bf16 + 4 weight transposes (fp32 [R][C] -> bf16 [C][R])
__global__ __launch_bounds__(256) void prep_kernel(const float* __restrict__ x,
                                                   const float* __restrict__ Wq,
                                                   const float* __restrict__ Wk,
                                                   const float* __restrict__ Wv,
                                                   const float* __restrict__ Wu,
                                                   unsigned short* __restrict__ xb,
                                                   unsigned short* __restrict__ wqkt,
                                                   unsigned short* __restrict__ wvt,
                                                   unsigned short* __restrict__ wut) {
  int bx = blockIdx.x;
  if (bx < 1024) {  // x convert, 4 elems/thread
    int i = (bx * 256 + threadIdx.x) * 4;
    float4 v = *(const float4*)(x + i);
    unsigned long long p = (unsigned long long)f2b(v.x) |
                           ((unsigned long long)f2b(v.y) << 16) |
                           ((unsigned long long)f2b(v.z) << 32) |
                           ((unsigned long long)f2b(v.w) << 48);
    *(unsigned long long*)(xb + i) = p;
    return;
  }
  __shared__ unsigned short T[64][65];
  const float* src;
  unsigned short* dst;
  int R, C, tile;
  if (bx < 1152)      { src = Wq; dst = wqkt;          R = 256;  C = 2048; tile = bx - 1024; }
  else if (bx < 1280) { src = Wk; dst = wqkt + 524288; R = 256;  C = 2048; tile = bx - 1152; }
  else if (bx < 1408) { src = Wv; dst = wvt;           R = 256;  C = 2048; tile = bx - 1280; }
  else                { src = Wu; dst = wut;           R = 2048; C = 256;  tile = bx - 1408; }
  int ctiles = C >> 6;
  int cx = tile % ctiles, ry = tile / ctiles;
  int r0 = ry * 64, c0 = cx * 64;
  int t = threadIdx.x;
#pragma unroll
  for (int i = 0; i < 16; ++i) {
    int idx = i * 256 + t;
    int r = idx >> 6, c = idx & 63;
    T[r][c] = f2b(src[(size_t)(r0 + r) * C + c0 + c]);
  }
  __syncthreads();
#pragma unroll
  for (int i = 0; i < 16; ++i) {
    int idx = i * 256 + t;
    int c = idx >> 6, r = idx & 63;
    dst[(size_t)(c0 + c) * R + r0 + r] = T[r][c];
  }
}

// ---- fused QKV projection: 128x128 tiles, Kt=256, DOUBLE-BUFFERED --------
// 1 barrier/iter: barrier drains DMA(cur), then DMA(next) issues and overlaps
// the MFMA phase. Q region pre-scaled 1/16 (exact 2^-4).
__global__ __launch_bounds__(256) void proj_kernel(const unsigned short* __restrict__ A,
                                                   const unsigned short* __restrict__ Bt,
                                                   unsigned short* __restrict__ qkb,
                                                   unsigned short* __restrict__ vtb) {
  __shared__ __align__(16) unsigned short SMEM[128 * 136];  // dbuf (32KB) | Vt (34.8KB)
  const int Kt = 256;
  int tid = threadIdx.x, lane = tid & 63, w = tid >> 6;
  int m16 = lane & 15, quad = lane >> 4;
  int wr = w & 1, wc = w >> 1;
  int m0 = blockIdx.y * 128, n0 = blockIdx.x * 128;
  int srow0 = w * 32 + (lane >> 2);
  int schunk = (lane & 3) ^ ((lane >> 2) & 3);
  floatx4 acc[4][4] = {};
  // prologue: stage k-tile 0 into buf 0
#pragma unroll
  for (int j = 0; j < 2; ++j) {
    int r = srow0 + j * 16;
    gl_lds16(A + (size_t)(m0 + r) * Kt + schunk * 8, &SMEM[(w * 32 + j * 16) * 32]);
    gl_lds16(Bt + (size_t)(n0 + r) * Kt + schunk * 8, &SMEM[4096 + (w * 32 + j * 16) * 32]);
  }
  for (int k0 = 0; k0 < Kt; k0 += 32) {
    int cur = (k0 >> 5) & 1;
    unsigned short* As = SMEM + cur * 8192;
    unsigned short* Bs = As + 4096;
    __syncthreads();  // drains DMA(cur); prior reads of (1-cur) done
    if (k0 + 32 < Kt) {
      unsigned short* Ad = SMEM + (1 - cur) * 8192;
      unsigned short* Bd = Ad + 4096;
#pragma unroll
      for (int j = 0; j < 2; ++j) {
        int r = srow0 + j * 16;
        gl_lds16(A + (size_t)(m0 + r) * Kt + k0 + 32 + schunk * 8, Ad + (w * 32 + j * 16) * 32);
        gl_lds16(Bt + (size_t)(n0 + r) * Kt + k0 + 32 + schunk * 8, Bd + (w * 32 + j * 16) * 32);
      }
    }
    int sw = (quad ^ (m16 & 3)) * 8;
    bf16x8 af[4], bfr[4];
#pragma unroll
    for (int i = 0; i < 4; ++i) {
      af[i]  = *(const bf16x8*)(&As[(wr * 64 + i * 16 + m16) * 32 + sw]);
      bfr[i] = *(const bf16x8*)(&Bs[(wc * 64 + i * 16 + m16) * 32 + sw]);
    }
#pragma unroll
    for (int i = 0; i < 4; ++i)
#pragma unroll
      for (int jn = 0; jn < 4; ++jn)
        acc[i][jn] = __builtin_amdgcn_mfma_f32_16x16x32_bf16(af[i], bfr[jn], acc[i][jn], 0, 0, 0);
  }
  if (n0 < 4096) {
    float qscale = (n0 < 2048) ? 0.0625f : 1.0f;
#pragma unroll
    for (int i = 0; i < 4; ++i)
#pragma unroll
      for (int jn = 0; jn < 4; ++jn)
#pragma unroll
        for (int r = 0; r < 4; ++r) {
          int m = m0 + wr * 64 + i * 16 + quad * 4 + r;
          int n = n0 + wc * 64 + jn * 16 + m16;
          qkb[(size_t)m * 4096 + n] = f2b(acc[i][jn][r] * qscale);
        }
  } else {  // V region: transpose tile in LDS, then coalesced 16B row writes
    __syncthreads();
    unsigned short* Vt = SMEM;  // [128 d][136]
#pragma unroll
    for (int i = 0; i < 4; ++i)
#pragma unroll
      for (int jn = 0; jn < 4; ++jn)
#pragma unroll
        for (int r = 0; r < 4; ++r) {
          int nn = wc * 64 + jn * 16 + m16;
          int mm = wr * 64 + i * 16 + quad * 4 + r;
          Vt[nn * 136 + mm] = f2b(acc[i][jn][r]);
        }
    __syncthreads();
    int bb = m0 >> 11, t0 = m0 & 2047;
#pragma unroll
    for (int i2 = 0; i2 < 8; ++i2) {
      int idx = i2 * 256 + tid;
      int nn = idx >> 4;
      int mc = (idx & 15) * 8;
      uint4 v = *(const uint4*)(&Vt[nn * 136 + mc]);
      *(uint4*)(&vtb[((size_t)(bb * 2048 + n0 - 4096 + nn)) * 2048 + t0 + mc]) = v;
    }
  }
}

// ---- out projection: 64x64 tiles, BK=128, DOUBLE-BUFFERED ----------------
__global__ __launch_bounds__(256) void out_kernel(const unsigned short* __restrict__ A,
                                                  const unsigned short* __restrict__ Bt,
                                                  float* __restrict__ Cout,
                                                  const float* __restrict__ bias) {
  __shared__ __align__(16) unsigned short SMEM[32768];  // 2 x (As 16KB + Bs 16KB)
  const int Kt = 2048;
  int tid = threadIdx.x, lane = tid & 63, w = tid >> 6;
  int m16 = lane & 15, quad = lane >> 4;
  int m0 = blockIdx.y * 64, n0 = blockIdx.x * 64;
  int srow_i = lane >> 4;
  int spos = lane & 15;
  int rsw = m16 & 7;
  floatx4 acc[4] = {};
  // prologue: stage k-tile 0 into buf 0
#pragma unroll
  for (int j = 0; j < 4; ++j) {
    int r = w * 16 + j * 4 + srow_i;
    gl_lds16(A + (size_t)(m0 + r) * Kt + ((spos ^ (r & 7)) * 8), &SMEM[(w * 16 + j * 4) * 128]);
    gl_lds16(Bt + (size_t)(n0 + r) * Kt + ((spos ^ (r & 7)) * 8), &SMEM[8192 + (w * 16 + j * 4) * 128]);
  }
  for (int k0 = 0; k0 < Kt; k0 += 128) {
    int cur = (k0 >> 7) & 1;
    unsigned short* As = SMEM + cur * 16384;
    unsigned short* Bs = As + 8192;
    __syncthreads();  // drains DMA(cur); prior reads of (1-cur) done
    if (k0 + 128 < Kt) {
      unsigned short* Ad = SMEM + (1 - cur) * 16384;
      unsigned short* Bd = Ad + 8192;
#pragma unroll
      for (int j = 0; j < 4; ++j) {
        int r = w * 16 + j * 4 + srow_i;
        gl_lds16(A + (size_t)(m0 + r) * Kt + k0 + 128 + ((spos ^ (r & 7)) * 8),
                 Ad + (w * 16 + j * 4) * 128);
        gl_lds16(Bt + (size_t)(n0 + r) * Kt + k0 + 128 + ((spos ^ (r & 7)) * 8),
                 Bd + (w * 16 + j * 4) * 128);
      }
    }
    bf16x8 af[4];
#pragma unroll
    for (int kk = 0; kk < 4; ++kk)
      af[kk] = *(const bf16x8*)(&As[(w * 16 + m16) * 128 + (((kk * 4 + quad) ^ rsw) * 8)]);
#pragma unroll
    for (int nt = 0; nt < 4; ++nt)
#pragma unroll
      for (int kk = 0; kk < 4; ++kk) {
        bf16x8 bfv = *(const bf16x8*)(&Bs[(nt * 16 + m16) * 128 + (((kk * 4 + quad) ^ rsw) * 8)]);
        acc[nt] = __builtin_amdgcn_mfma_f32_16x16x32_bf16(af[kk], bfv, acc[nt], 0, 0, 0);
      }
  }
#pragma unroll
  for (int nt = 0; nt < 4; ++nt)
#pragma unroll
    for (int r = 0; r < 4; ++r) {
      int m = m0 + w * 16 + quad * 4 + r;
      int n = n0 + nt * 16 + m16;
      Cout[(size_t)m * 256 + n] = acc[nt][r] + bias[n];
    }
}

// ---- flash attention v2.1: VALU rowsum (32 MFMA/iter, was 36) ------------
// 8 waves = 4 qg x 2 u; dbuf K/V DMA; 2 barriers/iter; shared P.
// l accumulated per-lane in fp32, reduced once in epilogue (butterfly + LDS).
__global__ __launch_bounds__(512, 2) void attn_kernel(const unsigned short* __restrict__ qk,
                                                      const unsigned short* __restrict__ vt,
                                                      unsigned short* __restrict__ ao) {
  __shared__ __align__(16) unsigned short Ks[2][64 * 256];  // 64 KB
  __shared__ __align__(16) unsigned short Vs[2][256 * 64];  // 64 KB
  __shared__ __align__(16) unsigned short Pb[4][32 * 72];   // 18.4 KB
  int tid = threadIdx.x, lane = tid & 63, w = tid >> 6;  // w 0..7
  int c32 = lane & 31, hi = lane >> 5;
  int qg = w & 3, u = w >> 2;
  int id = blockIdx.x;
  int xcd = id & 7, j = id >> 3;
  int bh = xcd + 8 * (j & 1);
  int q0 = (j >> 1) * 128;
  int b = bh >> 3, h = bh & 7;

  // Q A-frags: rows q0+qg*32+c32 (pre-scaled by 1/16 at proj)
  bf16x8 qf[16];
  const unsigned short* qrow =
      qk + (size_t)(b * 2048 + q0 + qg * 32 + c32) * 4096 + h * 256 + hi * 8;
#pragma unroll
  for (int kk = 0; kk < 16; ++kk) qf[kk] = *(const bf16x8*)(qrow + kk * 16);

  floatx16 O[4] = {};
  floatx16 lacc = {};  // per-lane rowsum partials (q rows x this lane's s col)

  const unsigned short* kbase = qk + (size_t)b * 2048 * 4096 + 2048 + h * 256;
  const unsigned short* vbase = vt + (size_t)bh * 256 * 2048;
  unsigned short* pq = &Pb[qg][0];

  int krow_i = lane >> 5, kpos = lane & 31;
  int vrow_i = lane >> 3, vpos = lane & 7;
  int ksw = c32 & 7;

  // prologue: stage tile 0 into buf 0
#pragma unroll
  for (int i = 0; i < 4; ++i) {
    int kr = i * 2 + krow_i;
    gl_lds16(kbase + (size_t)(w * 8 + kr) * 4096 + ((kpos ^ (kr & 7)) * 8),
             &Ks[0][(w * 8 + i * 2) * 256]);
    int vr = i * 8 + vrow_i;
    gl_lds16(vbase + (size_t)(w * 32 + vr) * 2048 + ((vpos ^ vrow_i) * 8),
             &Vs[0][(w * 32 + i * 8) * 64]);
  }

  for (int st = 0; st < 32; ++st) {
    int cur = st & 1;
    __syncthreads();  // drains DMA(cur), publishes

    // S[32q][32s] = Q K^T over this wave's s-half u  (C: row=q, col=s)
    floatx16 s = {};
    const unsigned short* krl = &Ks[cur][(u * 32 + c32) * 256];
#pragma unroll
    for (int kk = 0; kk < 16; ++kk) {
      bf16x8 kf = *(const bf16x8*)(krl + (((kk * 2 + hi) ^ ksw) * 8));
      s = __builtin_amdgcn_mfma_f32_32x32x16_bf16(qf[kk], kf, s, 0, 0, 0);
    }
    // no-max softmax; accumulate l in fp32; P -> per-qg shared LDS
#pragma unroll
    for (int i = 0; i < 16; ++i) {
      float p = __expf(s[i]);
      lacc[i] += p;
      int q = (i & 3) + 8 * (i >> 2) + 4 * hi;
      pq[q * 72 + u * 32 + c32] = f2b(p);
    }
    __syncthreads();  // P publish

    // DMA for st+1 into the idle buffer; drained at next top barrier
    if (st < 31) {
      int s0 = (st + 1) * 64;
      unsigned short* kdst = &Ks[1 - cur][0];
      unsigned short* vdst = &Vs[1 - cur][0];
#pragma unroll
      for (int i = 0; i < 4; ++i) {
        int kr = i * 2 + krow_i;
        gl_lds16(kbase + (size_t)(s0 + w * 8 + kr) * 4096 + ((kpos ^ (kr & 7)) * 8),
                 kdst + (w * 8 + i * 2) * 256);
        int vr = i * 8 + vrow_i;
        gl_lds16(vbase + (size_t)(w * 32 + vr) * 2048 + s0 + ((vpos ^ vrow_i) * 8),
                 vdst + (w * 32 + i * 8) * 64);
      }
    }

    // paf + PV for this wave's d-half u (full 64-s P from both u waves)
    bf16x8 paf[4];
#pragma unroll
    for (int f = 0; f < 4; ++f) paf[f] = *(const bf16x8*)(pq + c32 * 72 + f * 16 + hi * 8);
#pragma unroll
    for (int dt = 0; dt < 4; ++dt) {
      const unsigned short* vrl = &Vs[cur][(u * 128 + dt * 32 + c32) * 64];
#pragma unroll
      for (int f = 0; f < 4; ++f) {
        bf16x8 vf = *(const bf16x8*)(vrl + (((f * 2 + hi) ^ ksw) * 8));
        O[dt] = __builtin_amdgcn_mfma_f32_32x32x16_bf16(paf[f], vf, O[dt], 0, 0, 0);
      }
    }
  }

  // epilogue: reduce lacc across the 32 s-lanes, combine u-halves via LDS
#pragma unroll
  for (int off = 1; off < 32; off <<= 1)
#pragma unroll
    for (int i = 0; i < 16; ++i) lacc[i] += __shfl_xor(lacc[i], off);
  float* lsh = (float*)&Ks[0][0];  // [2 u][128 q]; K/V no longer needed
  __syncthreads();                 // all waves past last PV reads
  if (c32 == 0) {
#pragma unroll
    for (int i = 0; i < 16; ++i) {
      int q = (i & 3) + 8 * (i >> 2) + 4 * hi;
      lsh[u * 128 + qg * 32 + q] = lacc[i];
    }
  }
  __syncthreads();
#pragma unroll
  for (int dt = 0; dt < 4; ++dt)
#pragma unroll
    for (int i = 0; i < 16; ++i) {
      int q = (i & 3) + 8 * (i >> 2) + 4 * hi;
      float lr = 1.0f / (lsh[qg * 32 + q] + lsh[128 + qg * 32 + q]);
      ao[(size_t)(b * 2048 + q0 + qg * 32 + q) * 2048 + h * 256 + u * 128 + dt * 32 + c32] =
          f2b(O[dt][i] * lr);
    }
}

extern "C" void kernel_launch(void* const* d_in, const int* in_sizes, int n_in,
                              void* d_out, int out_size, void* d_ws, size_t ws_size,
                              hipStream_t stream) {
  const float* x  = (const float*)d_in[0];
  const float* Wq = (const float*)d_in[1];
  const float* Wk = (const float*)d_in[2];
  const float* Wv = (const float*)d_in[3];
  const float* Wu = (const float*)d_in[4];
  const float* bu = (const float*)d_in[5];

  unsigned short* xb   = (unsigned short*)d_ws;      // [4096][256]
  unsigned short* wqkt = xb + 1048576;               // [4096][256]  Wq^T | Wk^T
  unsigned short* wvt  = wqkt + 1048576;             // [2048][256]  Wv^T (contiguous)
  unsigned short* wut  = wvt + 524288;               // [256][2048]  Wu^T
  unsigned short* qkb  = wut + 524288;               // [4096][4096] q | k
  unsigned short* vtb  = qkb + 16777216;             // [16][256][2048] V^T
  unsigned short* aob  = vtb + 8388608;              // [4096][2048] attn out

  prep_kernel<<<1536, 256, 0, stream>>>(x, Wq, Wk, Wv, Wu, xb, wqkt, wvt, wut);
  proj_kernel<<<dim3(48, 32), 256, 0, stream>>>(xb, wqkt, qkb, vtb);
  attn_kernel<<<256, 512, 0, stream>>>(qkb, vtb, aob);
  out_kernel<<<dim3(4, 64), 256, 0, stream>>>(aob, wut, (float*)d_out, bu);
}